// Round 2
// baseline (848.344 us; speedup 1.0000x reference)
//
#include <hip/hip_runtime.h>
#include <hip/hip_bf16.h>
#include <stdint.h>

#define NTOK 4096
#define DIM  1024
#define TOPK 128
#define GBLK 32      // blocks in greedy kernel (all co-resident: 32 << 256 CUs)
#define COLS 128     // token columns per greedy block (GBLK*COLS == NTOK)
#define NEGM -1e30f

// ---------------------------------------------------------------------------
// k_prep: rel[n] = ((-a[n]) - min(-a) + 1e-6) / (max(-a) - min(-a))
// ---------------------------------------------------------------------------
__global__ __launch_bounds__(1024) void k_prep(const float* __restrict__ attn,
                                               float* __restrict__ rel) {
  __shared__ float smx[16], smn[16];
  int tid = threadIdx.x;
  float mx = -3.4e38f, mn = 3.4e38f;
  for (int n = tid; n < NTOK; n += 1024) {
    float a = attn[n];
    mx = fmaxf(mx, a); mn = fminf(mn, a);
  }
  for (int o = 32; o >= 1; o >>= 1) {
    mx = fmaxf(mx, __shfl_down(mx, o, 64));
    mn = fminf(mn, __shfl_down(mn, o, 64));
  }
  if ((tid & 63) == 0) { smx[tid >> 6] = mx; smn[tid >> 6] = mn; }
  __syncthreads();
  if (tid == 0) {
    float MX = smx[0], MN = smn[0];
    for (int w = 1; w < 16; ++w) { MX = fmaxf(MX, smx[w]); MN = fminf(MN, smn[w]); }
    smx[0] = MX; smn[0] = MN;
  }
  __syncthreads();
  float amax = smx[0], amin = smn[0];
  float rmin  = -amax;               // min of (-a)
  float range = (-amin) - rmin;      // max - min
  for (int n = tid; n < NTOK; n += 1024) {
    float r = -attn[n];
    rel[n] = ((r - rmin) + 1e-6f) / range;   // same op order as numpy
  }
}

// ---------------------------------------------------------------------------
// k_norm: xn[row] = x[row] / ||x[row]||   (one block per row, fp32)
// ---------------------------------------------------------------------------
__global__ __launch_bounds__(256) void k_norm(const float* __restrict__ x,
                                              float* __restrict__ xn) {
  __shared__ float ps[4];
  int row = blockIdx.x, tid = threadIdx.x;
  const float4* xr = (const float4*)(x + (size_t)row * DIM);
  float4 v = xr[tid];                           // 256 threads * 4 = 1024 elems
  float s = v.x * v.x + v.y * v.y + v.z * v.z + v.w * v.w;
  for (int o = 32; o >= 1; o >>= 1) s += __shfl_down(s, o, 64);
  if ((tid & 63) == 0) ps[tid >> 6] = s;
  __syncthreads();
  if (tid == 0) ps[0] = ps[0] + ps[1] + ps[2] + ps[3];
  __syncthreads();
  float nrm = sqrtf(ps[0]);                      // IEEE sqrt, then IEEE divide
  float4 o4;
  o4.x = v.x / nrm; o4.y = v.y / nrm; o4.z = v.z / nrm; o4.w = v.w / nrm;
  ((float4*)(xn + (size_t)row * DIM))[tid] = o4;
}

// ---------------------------------------------------------------------------
// k_gemm: ker[i][j] = rel[i] * (xn_i . xn_j) * rel[j], fp32, symmetric.
// 64x64 tile per block (256 thr, 4x4 microtile), BK=16, transposed LDS tiles.
// Only upper-triangle tiles computed; both halves written (bitwise-identical).
// ---------------------------------------------------------------------------
#define BK 16
__global__ __launch_bounds__(256) void k_gemm(const float* __restrict__ xn,
                                              const float* __restrict__ rel,
                                              float* __restrict__ ker) {
  int bi = blockIdx.y, bj = blockIdx.x;
  if (bi > bj) return;                        // symmetric: skip lower tiles
  __shared__ __align__(16) float As[BK][68];  // [k][row], padded vs bank conflicts
  __shared__ __align__(16) float Bs[BK][68];
  int tid = threadIdx.x;
  int tx = tid & 15, ty = tid >> 4;
  int lrow = tid >> 2, lkq = tid & 3;         // 64 rows x 4 k-quads per tile load
  const float* Ag = xn + ((size_t)(bi * 64 + lrow)) * DIM + lkq * 4;
  const float* Bg = xn + ((size_t)(bj * 64 + lrow)) * DIM + lkq * 4;
  float acc[4][4] = {};
  for (int kt = 0; kt < DIM; kt += BK) {
    float4 a4 = *(const float4*)(Ag + kt);
    float4 b4 = *(const float4*)(Bg + kt);
    __syncthreads();
    As[lkq * 4 + 0][lrow] = a4.x; As[lkq * 4 + 1][lrow] = a4.y;
    As[lkq * 4 + 2][lrow] = a4.z; As[lkq * 4 + 3][lrow] = a4.w;
    Bs[lkq * 4 + 0][lrow] = b4.x; Bs[lkq * 4 + 1][lrow] = b4.y;
    Bs[lkq * 4 + 2][lrow] = b4.z; Bs[lkq * 4 + 3][lrow] = b4.w;
    __syncthreads();
#pragma unroll
    for (int k = 0; k < BK; ++k) {
      float4 av = *(const float4*)&As[k][ty * 4];
      float4 bv = *(const float4*)&Bs[k][tx * 4];
      float a[4] = {av.x, av.y, av.z, av.w};
      float b[4] = {bv.x, bv.y, bv.z, bv.w};
#pragma unroll
      for (int r = 0; r < 4; ++r)
#pragma unroll
        for (int c = 0; c < 4; ++c) acc[r][c] += a[r] * b[c];
    }
  }
  float relr[4], relc[4];
#pragma unroll
  for (int r = 0; r < 4; ++r) relr[r] = rel[bi * 64 + ty * 4 + r];
#pragma unroll
  for (int c = 0; c < 4; ++c) relc[c] = rel[bj * 64 + tx * 4 + c];
#pragma unroll
  for (int r = 0; r < 4; ++r) {
#pragma unroll
    for (int c = 0; c < 4; ++c) {
      int gr = bi * 64 + ty * 4 + r, gc = bj * 64 + tx * 4 + c;
      // ker[n][m] = (rel_n * sim) * rel_m  -- reference's exact op order
      ker[(size_t)gr * NTOK + gc] = (acc[r][c] * relr[r]) * relc[c];
      ker[(size_t)gc * NTOK + gr] = (acc[r][c] * relc[c]) * relr[r];
    }
  }
}

// ---------------------------------------------------------------------------
// k_greedy: 128-step greedy DPP MAP. One token column per thread.
// One device-wide barrier per iteration (monotonic counter, pre-zeroed).
// Winner via packed atomicMax: (monotonic float key << 32) | (NTOK-1-n)
// so equal keys pick the SMALLEST n (np.argmax first-index tie-break).
// Cross-block cis traffic uses AGENT-scope atomics: per-XCD L2s are not
// coherent and cis aliases xn (whose stale lines sit in every L2 after gemm).
// ---------------------------------------------------------------------------
__global__ __launch_bounds__(128) void k_greedy(const float* __restrict__ ker,
                                                const float* __restrict__ feat,
                                                float* __restrict__ out,
                                                float* __restrict__ cis,
                                                unsigned long long* __restrict__ slots,
                                                unsigned* __restrict__ counter) {
  __shared__ float cisl[TOPK][COLS];            // block-local cis slice, fp32, 64 KB
  __shared__ float colbuf[TOPK];
  __shared__ unsigned long long red2[2];
  __shared__ unsigned long long bw;
  __shared__ int selj[TOPK];
  int tid = threadIdx.x;
  int blk = blockIdx.x;
  int n = blk * COLS + tid;                     // this thread's token
  float di2s = ker[(size_t)n * NTOK + n];       // diag of kernel

  for (int i = 0; i < TOPK; ++i) {
    // ---- local argmax (monotonic float->uint key, first-index tie-break)
    unsigned u = __float_as_uint(di2s);
    unsigned key = (u & 0x80000000u) ? ~u : (u | 0x80000000u);
    unsigned long long pk =
        ((unsigned long long)key << 32) | (unsigned)(NTOK - 1 - n);
    for (int o = 32; o >= 1; o >>= 1) {
      unsigned long long q = __shfl_down(pk, o, 64);
      if (q > pk) pk = q;
    }
    if ((tid & 63) == 0) red2[tid >> 6] = pk;
    __syncthreads();   // also: all lanes' cis stores of iter i-1 complete here
    if (tid == 0) {
      unsigned long long m = red2[0] > red2[1] ? red2[0] : red2[1];
      atomicMax(slots + i, m);                  // device-scope
      // release: publishes this block's iter-(i-1) cis stores + the atomicMax
      __hip_atomic_fetch_add(counter, 1u, __ATOMIC_RELEASE,
                             __HIP_MEMORY_SCOPE_AGENT);
      unsigned target = (unsigned)(i + 1) * GBLK;
      while (__hip_atomic_load(counter, __ATOMIC_ACQUIRE,
                               __HIP_MEMORY_SCOPE_AGENT) < target) {
        __builtin_amdgcn_s_sleep(2);
      }
      bw = __hip_atomic_load(slots + i, __ATOMIC_RELAXED,
                             __HIP_MEMORY_SCOPE_AGENT);
    }
    __syncthreads();
    unsigned long long w = bw;
    int j = NTOK - 1 - (int)(w & 0xffffffffu);
    unsigned kw = (unsigned)(w >> 32);
    unsigned du = (kw & 0x80000000u) ? (kw & 0x7fffffffu) : ~kw;
    float sd = sqrtf(__uint_as_float(du));      // sqrt(di2s[j]) pre-update
    if (tid == 0) selj[i] = j;
    // ---- kernel row j (coalesced 512B per block; kernel-boundary coherent)
    float kj = ker[(size_t)j * NTOK + n];
    // ---- fetch cis column j (t < i): agent-scope loads (coherence point)
    if (tid < i)
      colbuf[tid] = __hip_atomic_load(&cis[(size_t)tid * NTOK + j],
                                      __ATOMIC_RELAXED,
                                      __HIP_MEMORY_SCOPE_AGENT);
    __syncthreads();
    // ---- rank-i projection from block-local fp32 LDS cis
    float proj = 0.f;
    for (int t = 0; t < i; ++t)
      proj += colbuf[t] * cisl[t][tid];
    float eis = (kj - proj) / sd;
    // agent-scope store: must be visible to other XCDs next iteration
    __hip_atomic_store(&cis[(size_t)i * NTOK + n], eis, __ATOMIC_RELAXED,
                       __HIP_MEMORY_SCOPE_AGENT);
    cisl[i][tid] = eis;                         // fp32 local (for proj reads)
    di2s -= eis * eis;                          // reference updates all n first,
    if (n == j) di2s = NEGM;                    // then masks j
  }
  __syncthreads();
  // ---- gather output rows: block b copies rows k = b, b+GBLK, ...
  for (int k = blk; k < TOPK; k += GBLK) {
    int j = selj[k];
    const float4* src = (const float4*)(feat + (size_t)j * DIM);
    float4* dst = (float4*)(out + (size_t)k * DIM);
    for (int e = tid; e < DIM / 4; e += COLS) dst[e] = src[e];
  }
}

// ---------------------------------------------------------------------------
// ws layout (bytes):
//   [0,4)        sync counter        (zeroed each launch)
//   [256,1280)   128 x u64 winner slots (zeroed each launch)
//   [8192,...)   rel   : 4096 f32
//   [32768,...)  xn    : 4096*1024 f32 (16 MB) -- reused as cis (128x4096 f32)
//                        after gemm completes (stream-ordered, xn dead then)
//   [32768+16MB) ker   : 4096*4096 f32 (64 MB)
// total ~80 MB
// ---------------------------------------------------------------------------
extern "C" void kernel_launch(void* const* d_in, const int* in_sizes, int n_in,
                              void* d_out, int out_size, void* d_ws, size_t ws_size,
                              hipStream_t stream) {
  const float* feat = (const float*)d_in[0];
  const float* attn = (const float*)d_in[1];
  float* out = (float*)d_out;
  char* ws = (char*)d_ws;

  unsigned* counter = (unsigned*)ws;
  unsigned long long* slots = (unsigned long long*)(ws + 256);
  float* rel = (float*)(ws + 8192);
  float* xn  = (float*)(ws + 32768);
  float* cis = xn;  // aliases xn: greedy never reads xn, gemm done before greedy
  float* ker = (float*)(ws + 32768 + (size_t)NTOK * DIM * 4);

  hipMemsetAsync(d_ws, 0, 4096, stream);  // counter + slots
  k_prep<<<1, 1024, 0, stream>>>(attn, rel);
  k_norm<<<NTOK, 256, 0, stream>>>(feat, xn);
  k_gemm<<<dim3(64, 64), 256, 0, stream>>>(xn, rel, ker);
  k_greedy<<<GBLK, COLS, 0, stream>>>(ker, feat, out, cis, slots, counter);
}